// Round 9
// baseline (226.865 us; speedup 1.0000x reference)
//
#include <hip/hip_runtime.h>
#include <hip/hip_bf16.h>

#define BB 32
#define LL 1024
#define DD 64

typedef short bf16x8 __attribute__((ext_vector_type(8)));
typedef float f32x4 __attribute__((ext_vector_type(4)));

static __device__ __forceinline__ ushort f2bf(float x) {
  union { float f; unsigned u; } c; c.f = x;
  unsigned r = c.u + 0x7FFF + ((c.u >> 16) & 1);
  return (ushort)(r >> 16);
}

static __device__ __forceinline__ bf16x8 pack8(float4 a, float4 b) {
  union { __hip_bfloat162 h[4]; bf16x8 v; } r;
  r.h[0] = __float22bfloat162_rn({a.x, a.y});
  r.h[1] = __float22bfloat162_rn({a.z, a.w});
  r.h[2] = __float22bfloat162_rn({b.x, b.y});
  r.h[3] = __float22bfloat162_rn({b.z, b.w});
  return r.v;
}

// prep: K f32 [b][k][d] -> Kbf bf16 (same layout); V f32 [b][k][d] -> VT bf16 [b][d][k].
__global__ __launch_bounds__(256) void prep(const float* __restrict__ K,
                                            const float* __restrict__ V,
                                            ushort* __restrict__ Kbf,
                                            ushort* __restrict__ VT) {
  const int b = blockIdx.x, kt = blockIdx.y, t = threadIdx.x;

  const float* Ks = K + ((size_t)b * LL + kt * 64) * DD;
  ushort* Kd = Kbf + ((size_t)b * LL + kt * 64) * DD;
#pragma unroll
  for (int i = 0; i < 4; ++i) {
    int e = (i * 256 + t) * 4;
    float4 v = *(const float4*)(Ks + e);
    union { __hip_bfloat162 h[2]; uint2 q; } p;
    p.h[0] = __float22bfloat162_rn({v.x, v.y});
    p.h[1] = __float22bfloat162_rn({v.z, v.w});
    *(uint2*)(Kd + e) = p.q;
  }

  __shared__ ushort T[64][72];
  const float* Vb = V + ((size_t)b * LL + kt * 64) * DD;
#pragma unroll
  for (int i = 0; i < 4; ++i) {
    int kr = (t >> 4) + i * 16;
    int d0 = (t & 15) * 4;
    float4 v = *(const float4*)(Vb + kr * DD + d0);
    T[d0 + 0][kr] = f2bf(v.x);
    T[d0 + 1][kr] = f2bf(v.y);
    T[d0 + 2][kr] = f2bf(v.z);
    T[d0 + 3][kr] = f2bf(v.w);
  }
  __syncthreads();
  ushort* VTb = VT + (size_t)b * DD * LL + kt * 64;
#pragma unroll
  for (int i = 0; i < 2; ++i) {
    int d = (t >> 3) + i * 32;
    int s8 = (t & 7) * 8;
    *(uint4*)(VTb + (size_t)d * LL + s8) = *(const uint4*)(&T[d][s8]);
  }
}

// Fused attention. Block: 4 waves, one batch b, 16 query rows; waves split keys 4x256.
// Online softmax (local max per wave, one merge barrier); VT prefetched under softmax.
#define WSTR 1028  // Ws row stride (ushorts): conflict-free writes & b128 reads (measured 0)
__global__ __launch_bounds__(256, 4) void attn(
    const float* __restrict__ Q, const ushort* __restrict__ Kbf,
    const int* __restrict__ vlen, const ushort* __restrict__ VTg,
    float* __restrict__ outS, float* __restrict__ outW) {
  __shared__ __align__(16) ushort Ws[16][WSTR];  // 32,896 B
  __shared__ float redm[4][16];
  __shared__ float reds[4][16];

  const int b = blockIdx.x >> 6;
  const int q0 = (blockIdx.x & 63) << 4;
  const int tid = threadIdx.x;
  const int wv = tid >> 6, lane = tid & 63;
  const int quad = lane >> 4, n16 = lane & 15;
  const int vl = vlen[b];

  // A-frags from Q: A[m=n16][k=quad*8+j], second mfma k+32
  const float* Qp = Q + (size_t)(b * LL + q0 + n16) * DD + quad * 8;
  bf16x8 a0 = pack8(*(const float4*)Qp, *(const float4*)(Qp + 4));
  bf16x8 a1 = pack8(*(const float4*)(Qp + 32), *(const float4*)(Qp + 36));

  const ushort* Kb = Kbf + (size_t)b * LL * DD;
  const int kb = wv * 256 + n16;

  // ---- Phase 1: scores, 16 key-tiles of 16 per wave ----
  f32x4 acc[16];
#pragma unroll
  for (int t = 0; t < 16; ++t) {
    const ushort* Kp = Kb + (size_t)(kb + t * 16) * DD + quad * 8;
    f32x4 c = {0.f, 0.f, 0.f, 0.f};
    c = __builtin_amdgcn_mfma_f32_16x16x32_bf16(a0, *(const bf16x8*)Kp, c, 0, 0, 0);
    c = __builtin_amdgcn_mfma_f32_16x16x32_bf16(a1, *(const bf16x8*)(Kp + 32), c, 0, 0, 0);
    acc[t] = c;
  }

  // ---- Prefetch phase-2 VT group 0 NOW: hides L2 latency under softmax ----
  const ushort* VTb = VTg + (size_t)b * DD * LL + (size_t)(wv * 16 + n16) * LL;
  bf16x8 bvp[8];
#pragma unroll
  for (int i = 0; i < 8; ++i) bvp[i] = *(const bf16x8*)(VTb + i * 32 + quad * 8);

  // ---- local (per-wave-slab) softmax: no cross-wave wait before exp ----
  float pm[4] = {-3.0e38f, -3.0e38f, -3.0e38f, -3.0e38f};
#pragma unroll
  for (int t = 0; t < 16; ++t) {
    const bool valid = (kb + t * 16) < vl;
#pragma unroll
    for (int r = 0; r < 4; ++r) {
      float v = valid ? acc[t][r] * 0.125f : -1.0e6f;
      acc[t][r] = v;
      pm[r] = fmaxf(pm[r], v);
    }
  }
#pragma unroll
  for (int off = 1; off < 16; off <<= 1) {
#pragma unroll
    for (int r = 0; r < 4; ++r) pm[r] = fmaxf(pm[r], __shfl_xor(pm[r], off));
  }
  // pm[r] = local max over this wave's 256 keys. exp + local sum immediately.
  float ps[4] = {0.f, 0.f, 0.f, 0.f};
#pragma unroll
  for (int t = 0; t < 16; ++t) {
#pragma unroll
    for (int r = 0; r < 4; ++r) {
      float e = __expf(acc[t][r] - pm[r]);  // masked: exp(-1e6 - pm) == 0
      acc[t][r] = e;
      ps[r] += e;
    }
  }
#pragma unroll
  for (int off = 1; off < 16; off <<= 1) {
#pragma unroll
    for (int r = 0; r < 4; ++r) ps[r] += __shfl_xor(ps[r], off);
  }
  if (n16 == 0) {
#pragma unroll
    for (int r = 0; r < 4; ++r) {
      redm[wv][quad * 4 + r] = pm[r];
      reds[wv][quad * 4 + r] = ps[r];
    }
  }
  __syncthreads();  // single merge barrier

  // merge: gm = global max; tot = sum of rescaled local sums; f = own rescale/tot
  float f[4];
#pragma unroll
  for (int r = 0; r < 4; ++r) {
    int row = quad * 4 + r;
    float m0 = redm[0][row], m1 = redm[1][row], m2 = redm[2][row], m3 = redm[3][row];
    float gm = fmaxf(fmaxf(m0, m1), fmaxf(m2, m3));
    float tot = reds[0][row] * __expf(m0 - gm) + reds[1][row] * __expf(m1 - gm) +
                reds[2][row] * __expf(m2 - gm) + reds[3][row] * __expf(m3 - gm);
    f[r] = __expf(pm[r] - gm) / tot;
  }

  // W -> LDS bf16 (conflict-free)
#pragma unroll
  for (int t = 0; t < 16; ++t) {
#pragma unroll
    for (int r = 0; r < 4; ++r)
      Ws[quad * 4 + r][kb + t * 16] = f2bf(acc[t][r] * f[r]);
  }
  __syncthreads();

  // ---- Phase 2: O = W * V; dual acc chains; rolling VT prefetch ----
  f32x4 o0 = {0.f, 0.f, 0.f, 0.f}, o1 = {0.f, 0.f, 0.f, 0.f};
#pragma unroll
  for (int g = 0; g < 4; ++g) {
    bf16x8 bvn[8];
    if (g < 3) {
#pragma unroll
      for (int i = 0; i < 8; ++i)
        bvn[i] = *(const bf16x8*)(VTb + ((g + 1) * 8 + i) * 32 + quad * 8);
    }
    bf16x8 af[8];
#pragma unroll
    for (int i = 0; i < 8; ++i)
      af[i] = *(const bf16x8*)(&Ws[n16][(g * 8 + i) * 32 + quad * 8]);
#pragma unroll
    for (int i = 0; i < 8; ++i) {
      if (i & 1)
        o1 = __builtin_amdgcn_mfma_f32_16x16x32_bf16(af[i], bvp[i], o1, 0, 0, 0);
      else
        o0 = __builtin_amdgcn_mfma_f32_16x16x32_bf16(af[i], bvp[i], o0, 0, 0, 0);
    }
#pragma unroll
    for (int i = 0; i < 8; ++i) bvp[i] = bvn[i];
  }
#pragma unroll
  for (int r = 0; r < 4; ++r) {
    outS[(size_t)(b * LL + q0 + quad * 4 + r) * DD + wv * 16 + n16] = o0[r] + o1[r];
  }

  // ---- attn_w f32 store LAST, non-temporal (write-only data) ----
  {
    float* dstW = outW + (size_t)b * LL * LL + (size_t)q0 * LL;
#pragma unroll
    for (int i = 0; i < 16; ++i) {
      int j = i * 256 + tid;            // float4 index 0..4095
      int row = j >> 8, c4 = j & 255;
      uint2 u = *(const uint2*)(&Ws[row][c4 * 4]);
      f32x4 ov;
      union { unsigned q; float f; } w0, w1, w2, w3;
      w0.q = u.x << 16; w1.q = u.x & 0xffff0000u;
      w2.q = u.y << 16; w3.q = u.y & 0xffff0000u;
      ov[0] = w0.f; ov[1] = w1.f; ov[2] = w2.f; ov[3] = w3.f;
      __builtin_nontemporal_store(ov, (f32x4*)(dstW + (size_t)row * LL + c4 * 4));
    }
  }
}

extern "C" void kernel_launch(void* const* d_in, const int* in_sizes, int n_in,
                              void* d_out, int out_size, void* d_ws, size_t ws_size,
                              hipStream_t stream) {
  const float* Q = (const float*)d_in[0];
  const float* K = (const float*)d_in[1];
  const float* V = (const float*)d_in[2];
  const int* vl = (const int*)d_in[3];
  float* outS = (float*)d_out;                 // attn_score [32,1024,64] f32
  float* outW = outS + (size_t)BB * LL * DD;   // attn_w     [32,1024,1024] f32
  ushort* VT = (ushort*)d_ws;                  // 4 MB bf16 V^T
  ushort* Kbf = VT + (size_t)BB * DD * LL;     // 4 MB bf16 K

  prep<<<dim3(BB, 16), 256, 0, stream>>>(K, V, Kbf, VT);
  attn<<<dim3(BB * 64), 256, 0, stream>>>(Q, Kbf, vl, VT, outS, outW);
}